// Round 5
// baseline (246.198 us; speedup 1.0000x reference)
//
#include <hip/hip_runtime.h>
#include <cstddef>
#include <cstdint>

// LinearAttention MI355X round 5:
//  - qout: 32-token blocks (grid 2048), LDS 52.5KB -> 3 blocks/CU, acc[8][2]
//    -> ~155 unified regs -> 3 waves/SIMD. qsm packed ds_write_b32.
//  - kvctx: XCD-aware swizzle so 8 same-(b,seg) head-blocks share one XCD's L2
//    (XT was re-read 8x = 256MB from HBM).
//
// y = LN( U_b @ softmax_d(W_q X_b) + b_out ),  U_b = 0.125 * W_out ctx_b^T (per head)
// ctx_b[h,d,e] = (sum_n exp(K[d,n]) V[e,n]) / (Z_d * 4096)
//
// ws layout (bytes):
//   XTs  (bf16, swizzled [b][n][c]) : 0          .. 33,554,432
//   wbf  (bf16 wqkv)                : 33,554,432 .. 34,340,864
//   Ubf  (bf16 U)                   : 34,340,864 .. 38,535,168
//   Cp   (f32 ctx partials)         : 38,535,168 .. 46,923,776
//   Zp   (f32 Z partials)           : 46,923,776 .. 47,054,848

typedef __attribute__((ext_vector_type(8))) short s16x8;
typedef __attribute__((ext_vector_type(4))) float f32x4;

#define MFMA(a,b,c) __builtin_amdgcn_mfma_f32_16x16x32_bf16(a,b,c,0,0,0)

#define XT_BSTRIDE 1048576   // shorts per batch: 4096 tokens * 256 ch

__device__ __forceinline__ unsigned short f2bf(float f){
    union { float f; unsigned int u; } v; v.f = f;
    unsigned int u = v.u;
    unsigned int r = (u + 0x7FFFu + ((u >> 16) & 1u)) >> 16;   // RNE
    return (unsigned short)r;
}
__device__ __forceinline__ float bf2f(unsigned short b){
    union { unsigned int u; float f; } v; v.u = ((unsigned int)b) << 16;
    return v.f;
}
__device__ __forceinline__ void gload_lds16(const void* g, void* l){
    __builtin_amdgcn_global_load_lds(
        (const __attribute__((address_space(1))) unsigned int*)g,
        (__attribute__((address_space(3))) unsigned int*)l, 16, 0, 0);
}

// ------------- prep: x [b][c][n] f32 -> XT [b][n][c] bf16, block-swizzled ----
__global__ __launch_bounds__(256)
void xprep_kernel(const float* __restrict__ x, unsigned short* __restrict__ XT)
{
    __shared__ float xt[64*68];
    const int tid = threadIdx.x;
    const int n0 = blockIdx.x * 64;
    const int c0 = blockIdx.y * 64;
    const int b  = blockIdx.z;
    {
        const int ci = tid >> 2, ng = tid & 3;
        const float* xs = x + (size_t)b*1048576 + (size_t)(c0+ci)*4096 + n0 + ng*16;
        #pragma unroll
        for (int k=0;k<4;++k){
            float4 v = *(const float4*)(xs + k*4);
            *(float4*)&xt[ci*68 + ng*16 + k*4] = v;
        }
    }
    __syncthreads();
    const int nr = tid >> 2, cg = tid & 3;
    const int n = n0 + nr;
    unsigned short* dstrow = XT + (size_t)b*XT_BSTRIDE + (size_t)n*256;
    #pragma unroll
    for (int t2=0;t2<2;++t2){
        s16x8 pk;
        #pragma unroll
        for (int j=0;j<8;++j){
            int c = cg*16 + t2*8 + j;
            pk[j] = (short)f2bf(xt[c*68 + nr]);
        }
        int blk = (((c0>>3) + cg*2 + t2) ^ (n & 7));
        *(s16x8*)(dstrow + blk*8) = pk;
    }
}

// ------------- prep: wqkv f32 -> bf16 ---------------------------------------
__global__ __launch_bounds__(256)
void wprep_kernel(const float* __restrict__ w, unsigned short* __restrict__ wb)
{
    int i = (blockIdx.x*256 + threadIdx.x) * 8;    // 393216 elems, grid 192
    float4 a = *(const float4*)(w + i);
    float4 b = *(const float4*)(w + i + 4);
    s16x8 pk;
    pk[0]=(short)f2bf(a.x); pk[1]=(short)f2bf(a.y); pk[2]=(short)f2bf(a.z); pk[3]=(short)f2bf(a.w);
    pk[4]=(short)f2bf(b.x); pk[5]=(short)f2bf(b.y); pk[6]=(short)f2bf(b.z); pk[7]=(short)f2bf(b.w);
    *(s16x8*)(wb + i) = pk;
}

// ------------- kernel A: KV MFMA GEMM + exp + partial context ---------------
// grid 512 linear (XCD-swizzled), 256 thr. LDS: xtile 32768 + kv 18432 = 51200
__global__ __launch_bounds__(256,2)
void kvctx_kernel(const unsigned short* __restrict__ XT, const unsigned short* __restrict__ wb,
                  float* __restrict__ Cp, float* __restrict__ Zp)
{
    extern __shared__ char smraw[];
    unsigned short* xtile = (unsigned short*)smraw;            // [64][256]
    unsigned short* kv    = (unsigned short*)(smraw + 32768);  // [128][72]

    const int tid = threadIdx.x;
    const int w = tid >> 6, lane = tid & 63;
    const int l15 = lane & 15, q = lane >> 4;
    // XCD swizzle: flat%8 ~ XCD. qb = (b,seg) group shares an XCD across its
    // 8 head-blocks -> the 512KB XT slice stays in that XCD's L2.
    const int flat = blockIdx.x;
    const int qb  = flat & 63;     // b*4 + seg
    const int h   = flat >> 6;     // head
    const int b   = qb >> 2;
    const int seg = qb & 3;
    const int bh  = b*8 + h;

    // persistent W fragments: wave w owns KV rows w*32..w*32+31
    s16x8 aW[2][8];
    #pragma unroll
    for (int mf=0;mf<2;++mf){
        int rl = w*32 + mf*16 + l15;
        int grow = (rl < 64) ? (512 + h*64 + rl) : (1024 + h*64 + (rl-64));
        const unsigned short* wr = wb + (size_t)grow*256 + q*8;
        #pragma unroll
        for (int kc=0;kc<8;++kc)
            aW[mf][kc] = *(const s16x8*)(wr + kc*32);
    }

    f32x4 ctxacc[4];
    #pragma unroll
    for (int ef=0;ef<4;++ef) ctxacc[ef] = (f32x4){0.f,0.f,0.f,0.f};
    float zacc[8];
    #pragma unroll
    for (int i=0;i<8;++i) zacc[i]=0.f;

    const unsigned short* gsrc0 = XT + (size_t)b*XT_BSTRIDE + (size_t)(seg*1024)*256;

    {   // stage chunk 0
        const unsigned short* gs = gsrc0 + w*4096 + lane*8;
        #pragma unroll
        for (int j=0;j<8;++j)
            gload_lds16(gs + j*512, &xtile[w*4096 + j*512]);
    }
    __syncthreads();

    #pragma unroll 1
    for (int t=0;t<16;++t){
        // ---- KV GEMM (128 x 64 tile)
        f32x4 acc[2][4];
        #pragma unroll
        for (int mf=0;mf<2;++mf)
            #pragma unroll
            for (int nf=0;nf<4;++nf) acc[mf][nf]=(f32x4){0.f,0.f,0.f,0.f};
        #pragma unroll
        for (int kc=0;kc<8;++kc){
            s16x8 bf[4];
            #pragma unroll
            for (int nf=0;nf<4;++nf){
                int nl = nf*16 + l15;
                int blk = (kc*4 + q) ^ (nl & 7);
                bf[nf] = *(const s16x8*)&xtile[nl*256 + blk*8];
            }
            #pragma unroll
            for (int mf=0;mf<2;++mf)
                #pragma unroll
                for (int nf=0;nf<4;++nf)
                    acc[mf][nf] = MFMA(aW[mf][kc], bf[nf], acc[mf][nf]);
        }
        // ---- exp (K waves) + write KV tile to LDS [row][72]
        #pragma unroll
        for (int mf=0;mf<2;++mf){
            int row = w*32 + mf*16 + q*4;
            #pragma unroll
            for (int nf=0;nf<4;++nf){
                int col = nf*16 + l15;
                #pragma unroll
                for (int r=0;r<4;++r){
                    float v = acc[mf][nf][r];
                    if (w < 2){
                        v = __expf(v);
                        unsigned short bv = f2bf(v);
                        zacc[mf*4+r] += bf2f(bv);
                        kv[(row+r)*72 + col] = bv;
                    } else {
                        kv[(row+r)*72 + col] = f2bf(v);
                    }
                }
            }
        }
        __syncthreads();
        if (t < 15){   // prefetch next X tile, overlapped with ctx GEMM
            const unsigned short* gs = gsrc0 + (t+1)*16384 + w*4096 + lane*8;
            #pragma unroll
            for (int j=0;j<8;++j)
                gload_lds16(gs + j*512, &xtile[w*4096 + j*512]);
        }
        // ---- ctx GEMM: ctx[d,e] += expK[d,n] * V[e,n]
        #pragma unroll
        for (int kf=0;kf<2;++kf){
            s16x8 aC = *(const s16x8*)&kv[(w*16 + l15)*72 + kf*32 + q*8];
            #pragma unroll
            for (int ef=0;ef<4;++ef){
                s16x8 bC = *(const s16x8*)&kv[(64 + ef*16 + l15)*72 + kf*32 + q*8];
                ctxacc[ef] = MFMA(aC, bC, ctxacc[ef]);
            }
        }
        __syncthreads();
    }

    float* cpb = Cp + (size_t)(bh*4 + seg)*4096;
    #pragma unroll
    for (int ef=0;ef<4;++ef)
        #pragma unroll
        for (int r=0;r<4;++r){
            int d = w*16 + q*4 + r;
            cpb[d*64 + ef*16 + l15] = ctxacc[ef][r];
        }
    if (w < 2){
        #pragma unroll
        for (int i=0;i<8;++i){
            #pragma unroll
            for (int off=1; off<16; off<<=1)
                zacc[i] += __shfl_xor(zacc[i], off, 64);
        }
        if (l15 == 0){
            float* zpb = Zp + (size_t)(bh*4 + seg)*64;
            #pragma unroll
            for (int mf=0;mf<2;++mf)
                #pragma unroll
                for (int r=0;r<4;++r)
                    zpb[w*32 + mf*16 + q*4 + r] = zacc[mf*4+r];
        }
    }
}

// ------------- kernel B: reduce Cp/Zp + U = 0.125 * W_out ctx^T -------------
// grid (8 h, 16 b), 256 thr; LDS dyn 83456 B
__global__ __launch_bounds__(256)
void ctxu_kernel(const float* __restrict__ Cp, const float* __restrict__ Zp,
                 const float* __restrict__ wout, unsigned short* __restrict__ U)
{
    extern __shared__ char smraw[];
    float* wl = (float*)smraw;                  // [256][65]
    float* cl = (float*)(smraw + 66560);        // [64][65]
    float* zi = (float*)(smraw + 83200);        // [64]
    const int h = blockIdx.x, b = blockIdx.y, tid = threadIdx.x;
    const int bh = b*8 + h;
    {
        const float* wsrc = wout + (size_t)tid*512 + h*64;
        #pragma unroll
        for (int j=0;j<16;++j){
            float4 v = *(const float4*)(wsrc + j*4);
            wl[tid*65 + j*4+0]=v.x; wl[tid*65 + j*4+1]=v.y;
            wl[tid*65 + j*4+2]=v.z; wl[tid*65 + j*4+3]=v.w;
        }
    }
    if (tid < 64){
        float zs = 0.f;
        #pragma unroll
        for (int s=0;s<4;++s) zs += Zp[(bh*4+s)*64 + tid];
        zi[tid] = 1.f / (zs * 4096.f);
    }
    __syncthreads();
    {
        const int d = tid >> 2, e0 = (tid & 3) * 16;
        const float* cb = Cp + (size_t)(bh*4)*4096 + d*64 + e0;
        float v[16];
        #pragma unroll
        for (int j=0;j<16;++j) v[j]=0.f;
        #pragma unroll
        for (int s=0;s<4;++s){
            #pragma unroll
            for (int j4=0;j4<4;++j4){
                float4 t = *(const float4*)(cb + (size_t)s*4096 + j4*4);
                v[j4*4+0]+=t.x; v[j4*4+1]+=t.y; v[j4*4+2]+=t.z; v[j4*4+3]+=t.w;
            }
        }
        float zv = zi[d];
        #pragma unroll
        for (int j=0;j<16;++j) cl[d*65 + e0 + j] = v[j] * zv;
    }
    __syncthreads();
    const int d = tid & 63, og = tid >> 6;
    unsigned short* ub = U + (size_t)b*131072;
    #pragma unroll 1
    for (int k=0;k<64;++k){
        int o = og*64 + k;
        float s = 0.f;
        #pragma unroll
        for (int e=0;e<64;++e) s += wl[o*65+e]*cl[d*65+e];
        ub[(size_t)o*512 + h*64 + d] = f2bf(s * 0.125f);
    }
}

// ------------- kernel C: q MFMA -> softmax_d -> U MFMA -> bias -> LN --------
// grid (128 ntiles, 16 b), 256 thr, 32 tokens/block. LDS dyn 52480 B:
//   xtile [32][256] bf16 : 0     .. 16384
//   qsm   [32][516] bf16 : 16384 .. 49408
//   red   [4][32][2] f32 : 49408 .. 50432
//   bl    [256] f32      : 50432 .. 51456
//   gl    [256] f32      : 51456 .. 52480
__global__ __launch_bounds__(256,3)
void qout_kernel(const unsigned short* __restrict__ XT, const unsigned short* __restrict__ wb,
                 const unsigned short* __restrict__ U, const float* __restrict__ bout,
                 const float* __restrict__ gg, float* __restrict__ out)
{
    extern __shared__ char smraw[];
    unsigned short* xtile = (unsigned short*)smraw;
    unsigned short* qsm   = (unsigned short*)(smraw + 16384);
    float* red = (float*)(smraw + 49408);
    float* bl  = (float*)(smraw + 50432);
    float* gl  = (float*)(smraw + 51456);

    const int tid = threadIdx.x;
    const int w = tid >> 6, lane = tid & 63, l15 = lane & 15, q = lane >> 4;
    const int b = blockIdx.y;
    const int n0 = blockIdx.x * 32;

    bl[tid] = bout[tid];
    gl[tid] = gg[tid];
    {
        const unsigned short* gs = XT + (size_t)b*XT_BSTRIDE + (size_t)n0*256 + w*2048 + lane*8;
        #pragma unroll
        for (int j=0;j<4;++j)
            gload_lds16(gs + j*512, &xtile[w*2048 + j*512]);
    }
    __syncthreads();

    // ---- q GEMM: wave w owns q rows w*128..+127, N=32, pipelined prefetch
    f32x4 acc[8][2];
    #pragma unroll
    for (int mf=0;mf<8;++mf)
        #pragma unroll
        for (int nf=0;nf<2;++nf) acc[mf][nf]=(f32x4){0.f,0.f,0.f,0.f};

    const unsigned short* wq = wb + (size_t)(w*128 + l15)*256 + q*8;
    s16x8 avA[8], avB[8];
    #pragma unroll
    for (int mf=0;mf<8;++mf) avA[mf] = *(const s16x8*)(wq + (size_t)mf*16*256);

    #pragma unroll 1
    for (int kc=0; kc<8; kc+=2){
        #pragma unroll
        for (int mf=0;mf<8;++mf) avB[mf] = *(const s16x8*)(wq + (size_t)mf*16*256 + (kc+1)*32);
        {
            s16x8 bf[2];
            #pragma unroll
            for (int nf=0;nf<2;++nf){
                int nl = nf*16 + l15;
                int blk = (kc*4 + q) ^ (nl & 7);
                bf[nf] = *(const s16x8*)&xtile[nl*256 + blk*8];
            }
            __builtin_amdgcn_s_setprio(1);
            #pragma unroll
            for (int mf=0;mf<8;++mf)
                #pragma unroll
                for (int nf=0;nf<2;++nf)
                    acc[mf][nf] = MFMA(avA[mf], bf[nf], acc[mf][nf]);
            __builtin_amdgcn_s_setprio(0);
        }
        if (kc+2 < 8){
            #pragma unroll
            for (int mf=0;mf<8;++mf) avA[mf] = *(const s16x8*)(wq + (size_t)mf*16*256 + (kc+2)*32);
        }
        {
            s16x8 bf[2];
            #pragma unroll
            for (int nf=0;nf<2;++nf){
                int nl = nf*16 + l15;
                int blk = ((kc+1)*4 + q) ^ (nl & 7);
                bf[nf] = *(const s16x8*)&xtile[nl*256 + blk*8];
            }
            __builtin_amdgcn_s_setprio(1);
            #pragma unroll
            for (int mf=0;mf<8;++mf)
                #pragma unroll
                for (int nf=0;nf<2;++nf)
                    acc[mf][nf] = MFMA(avB[mf], bf[nf], acc[mf][nf]);
            __builtin_amdgcn_s_setprio(0);
        }
    }

    // ---- softmax over d, per head per column (scale folded into U)
    #pragma unroll
    for (int hh=0;hh<2;++hh){
        #pragma unroll
        for (int nf=0;nf<2;++nf){
            float m = -1e30f;
            #pragma unroll
            for (int mf=0;mf<4;++mf)
                #pragma unroll
                for (int r=0;r<4;++r)
                    m = fmaxf(m, acc[hh*4+mf][nf][r]);
            m = fmaxf(m, __shfl_xor(m, 16, 64));
            m = fmaxf(m, __shfl_xor(m, 32, 64));
            float s = 0.f;
            #pragma unroll
            for (int mf=0;mf<4;++mf)
                #pragma unroll
                for (int r=0;r<4;++r){
                    float e = __expf(acc[hh*4+mf][nf][r] - m);
                    acc[hh*4+mf][nf][r] = e;
                    s += e;
                }
            s += __shfl_xor(s, 16, 64);
            s += __shfl_xor(s, 32, 64);
            float rs = 1.f / s;
            #pragma unroll
            for (int mf=0;mf<4;++mf)
                #pragma unroll
                for (int r=0;r<4;++r)
                    acc[hh*4+mf][nf][r] *= rs;
        }
    }
    // ---- pack qsm[n][k] as b32 pairs (no barrier needed: disjoint region)
    #pragma unroll
    for (int mf=0;mf<8;++mf){
        int kbase = w*128 + mf*16 + q*4;
        #pragma unroll
        for (int nf=0;nf<2;++nf){
            int n = nf*16 + l15;
            unsigned int w0 = (unsigned int)f2bf(acc[mf][nf][0]) | ((unsigned int)f2bf(acc[mf][nf][1]) << 16);
            unsigned int w1 = (unsigned int)f2bf(acc[mf][nf][2]) | ((unsigned int)f2bf(acc[mf][nf][3]) << 16);
            *(unsigned int*)&qsm[n*516 + kbase]     = w0;
            *(unsigned int*)&qsm[n*516 + kbase + 2] = w1;
        }
    }
    __syncthreads();

    // ---- U GEMM: wave w owns out rows w*64..+63, N=32, pipelined prefetch
    f32x4 yacc[4][2];
    #pragma unroll
    for (int mf=0;mf<4;++mf)
        #pragma unroll
        for (int nf=0;nf<2;++nf) yacc[mf][nf]=(f32x4){0.f,0.f,0.f,0.f};
    const unsigned short* Ub = U + (size_t)b*131072 + (size_t)(w*64 + l15)*512 + q*8;
    s16x8 uvA[4], uvB[4];
    #pragma unroll
    for (int mf=0;mf<4;++mf) uvA[mf] = *(const s16x8*)(Ub + (size_t)mf*16*512);

    #pragma unroll 1
    for (int kc=0; kc<16; kc+=2){
        #pragma unroll
        for (int mf=0;mf<4;++mf) uvB[mf] = *(const s16x8*)(Ub + (size_t)mf*16*512 + (kc+1)*32);
        {
            s16x8 bf[2];
            #pragma unroll
            for (int nf=0;nf<2;++nf){
                int n = nf*16 + l15;
                bf[nf] = *(const s16x8*)&qsm[n*516 + kc*32 + q*8];
            }
            __builtin_amdgcn_s_setprio(1);
            #pragma unroll
            for (int mf=0;mf<4;++mf)
                #pragma unroll
                for (int nf=0;nf<2;++nf)
                    yacc[mf][nf] = MFMA(uvA[mf], bf[nf], yacc[mf][nf]);
            __builtin_amdgcn_s_setprio(0);
        }
        if (kc+2 < 16){
            #pragma unroll
            for (int mf=0;mf<4;++mf) uvA[mf] = *(const s16x8*)(Ub + (size_t)mf*16*512 + (kc+2)*32);
        }
        {
            s16x8 bf[2];
            #pragma unroll
            for (int nf=0;nf<2;++nf){
                int n = nf*16 + l15;
                bf[nf] = *(const s16x8*)&qsm[n*516 + (kc+1)*32 + q*8];
            }
            __builtin_amdgcn_s_setprio(1);
            #pragma unroll
            for (int mf=0;mf<4;++mf)
                #pragma unroll
                for (int nf=0;nf<2;++nf)
                    yacc[mf][nf] = MFMA(uvB[mf], bf[nf], yacc[mf][nf]);
            __builtin_amdgcn_s_setprio(0);
        }
    }
    // ---- bias
    #pragma unroll
    for (int mf=0;mf<4;++mf){
        int ob = w*64 + mf*16 + q*4;
        #pragma unroll
        for (int r=0;r<4;++r){
            float bo = bl[ob + r];
            #pragma unroll
            for (int nf=0;nf<2;++nf) yacc[mf][nf][r] += bo;
        }
    }
    // ---- LayerNorm over 256 channels (4 waves each own 64 channels)
    float s1[2], s2[2];
    #pragma unroll
    for (int nf=0;nf<2;++nf){ s1[nf]=0.f; s2[nf]=0.f; }
    #pragma unroll
    for (int mf=0;mf<4;++mf)
        #pragma unroll
        for (int nf=0;nf<2;++nf)
            #pragma unroll
            for (int r=0;r<4;++r){
                float v = yacc[mf][nf][r];
                s1[nf] += v; s2[nf] += v*v;
            }
    #pragma unroll
    for (int nf=0;nf<2;++nf){
        s1[nf] += __shfl_xor(s1[nf], 16, 64);
        s1[nf] += __shfl_xor(s1[nf], 32, 64);
        s2[nf] += __shfl_xor(s2[nf], 16, 64);
        s2[nf] += __shfl_xor(s2[nf], 32, 64);
    }
    if (q == 0){
        #pragma unroll
        for (int nf=0;nf<2;++nf){
            int col = nf*16 + l15;
            red[(w*32 + col)*2 + 0] = s1[nf];
            red[(w*32 + col)*2 + 1] = s2[nf];
        }
    }
    __syncthreads();
    float mean_[2], inv_[2];
    #pragma unroll
    for (int nf=0;nf<2;++nf){
        int col = nf*16 + l15;
        float S1 = red[col*2] + red[(32+col)*2] + red[(64+col)*2] + red[(96+col)*2];
        float S2 = red[col*2+1] + red[(32+col)*2+1] + red[(64+col)*2+1] + red[(96+col)*2+1];
        float mn = S1 * (1.f/256.f);
        float vr = S2 * (1.f/256.f) - mn*mn;
        mean_[nf] = mn;
        inv_[nf] = rsqrtf(vr + 1e-5f);
    }
    float* ob = out + (size_t)b*1048576 + n0;
    #pragma unroll
    for (int mf=0;mf<4;++mf){
        #pragma unroll
        for (int r=0;r<4;++r){
            int o = w*64 + mf*16 + q*4 + r;
            float gv = gl[o];
            #pragma unroll
            for (int nf=0;nf<2;++nf){
                float val = (yacc[mf][nf][r] - mean_[nf]) * inv_[nf] * gv;
                ob[(size_t)o*4096 + nf*16 + l15] = val;
            }
        }
    }
}

// ----------------------------------------------------------------------------
extern "C" void kernel_launch(void* const* d_in, const int* in_sizes, int n_in,
                              void* d_out, int out_size, void* d_ws, size_t ws_size,
                              hipStream_t stream)
{
    const float* x    = (const float*)d_in[0];
    const float* wqkv = (const float*)d_in[1];
    const float* wout = (const float*)d_in[2];
    const float* bout = (const float*)d_in[3];
    const float* g    = (const float*)d_in[4];
    float* out = (float*)d_out;

    char* wsb = (char*)d_ws;
    unsigned short* XTs = (unsigned short*)wsb;
    unsigned short* wbf = (unsigned short*)(wsb + 33554432);
    unsigned short* Ubf = (unsigned short*)(wsb + 34340864);
    float* Cp  = (float*)(wsb + 38535168);
    float* Zp  = (float*)(wsb + 46923776);

    hipLaunchKernelGGL(xprep_kernel, dim3(64, 4, 16), dim3(256), 0,     stream, x, XTs);
    hipLaunchKernelGGL(wprep_kernel, dim3(192),       dim3(256), 0,     stream, wqkv, wbf);
    hipLaunchKernelGGL(kvctx_kernel, dim3(512),       dim3(256), 51200, stream, XTs, wbf, Cp, Zp);
    hipLaunchKernelGGL(ctxu_kernel,  dim3(8, 16),     dim3(256), 83456, stream, Cp, Zp, wout, Ubf);
    hipLaunchKernelGGL(qout_kernel,  dim3(128, 16),   dim3(256), 52480, stream, XTs, wbf, Ubf, bout, g, out);
}

// Round 6
// 192.503 us; speedup vs baseline: 1.2789x; 1.2789x over previous
//
#include <hip/hip_runtime.h>
#include <hip/hip_bf16.h>
#include <cstddef>
#include <cstdint>

// LinearAttention MI355X round 6:
//  - qout: revert to round-4 geometry (N=64, 2 blocks/CU). Changes:
//    (a) qsm pack via v_cvt_pk (float22bfloat162_rn) + ds_write_b64 (32 vs 128 ops),
//    (b) pre-issue first q-weight frags before xtile barrier and first two U
//        k-slices before the qsm barrier (latency hides under pack+barrier),
//    (c) U-GEMM kc loop fully unrolled -> LLVM schedules loads to reg budget.
//  - kvctx: round-5 XCD-swizzled linear grid (neutral, kept).
//
// y = LN( U_b @ softmax_d(W_q X_b) + b_out ),  U_b = 0.125 * W_out ctx_b^T (per head)
// ctx_b[h,d,e] = (sum_n exp(K[d,n]) V[e,n]) / (Z_d * 4096)
//
// ws layout (bytes):
//   XTs  (bf16, swizzled [b][n][c]) : 0          .. 33,554,432
//   wbf  (bf16 wqkv)                : 33,554,432 .. 34,340,864
//   Ubf  (bf16 U)                   : 34,340,864 .. 38,535,168
//   Cp   (f32 ctx partials)         : 38,535,168 .. 46,923,776
//   Zp   (f32 Z partials)           : 46,923,776 .. 47,054,848

typedef __attribute__((ext_vector_type(8))) short s16x8;
typedef __attribute__((ext_vector_type(4))) float f32x4;

#define MFMA(a,b,c) __builtin_amdgcn_mfma_f32_16x16x32_bf16(a,b,c,0,0,0)

#define XT_BSTRIDE 1048576   // shorts per batch: 4096 tokens * 256 ch

__device__ __forceinline__ unsigned short f2bf(float f){
    union { float f; unsigned int u; } v; v.f = f;
    unsigned int u = v.u;
    unsigned int r = (u + 0x7FFFu + ((u >> 16) & 1u)) >> 16;   // RNE
    return (unsigned short)r;
}
__device__ __forceinline__ float bf2f(unsigned short b){
    union { unsigned int u; float f; } v; v.u = ((unsigned int)b) << 16;
    return v.f;
}
__device__ __forceinline__ unsigned int pack2bf(float a, float b){
    __hip_bfloat162 h = __float22bfloat162_rn(make_float2(a, b));
    union { __hip_bfloat162 h; unsigned int u; } v; v.h = h;
    return v.u;
}
__device__ __forceinline__ void gload_lds16(const void* g, void* l){
    __builtin_amdgcn_global_load_lds(
        (const __attribute__((address_space(1))) unsigned int*)g,
        (__attribute__((address_space(3))) unsigned int*)l, 16, 0, 0);
}

// ------------- prep: x [b][c][n] f32 -> XT [b][n][c] bf16, block-swizzled ----
__global__ __launch_bounds__(256)
void xprep_kernel(const float* __restrict__ x, unsigned short* __restrict__ XT)
{
    __shared__ float xt[64*68];
    const int tid = threadIdx.x;
    const int n0 = blockIdx.x * 64;
    const int c0 = blockIdx.y * 64;
    const int b  = blockIdx.z;
    {
        const int ci = tid >> 2, ng = tid & 3;
        const float* xs = x + (size_t)b*1048576 + (size_t)(c0+ci)*4096 + n0 + ng*16;
        #pragma unroll
        for (int k=0;k<4;++k){
            float4 v = *(const float4*)(xs + k*4);
            *(float4*)&xt[ci*68 + ng*16 + k*4] = v;
        }
    }
    __syncthreads();
    const int nr = tid >> 2, cg = tid & 3;
    const int n = n0 + nr;
    unsigned short* dstrow = XT + (size_t)b*XT_BSTRIDE + (size_t)n*256;
    #pragma unroll
    for (int t2=0;t2<2;++t2){
        s16x8 pk;
        #pragma unroll
        for (int j=0;j<8;++j){
            int c = cg*16 + t2*8 + j;
            pk[j] = (short)f2bf(xt[c*68 + nr]);
        }
        int blk = (((c0>>3) + cg*2 + t2) ^ (n & 7));
        *(s16x8*)(dstrow + blk*8) = pk;
    }
}

// ------------- prep: wqkv f32 -> bf16 ---------------------------------------
__global__ __launch_bounds__(256)
void wprep_kernel(const float* __restrict__ w, unsigned short* __restrict__ wb)
{
    int i = (blockIdx.x*256 + threadIdx.x) * 8;    // 393216 elems, grid 192
    float4 a = *(const float4*)(w + i);
    float4 b = *(const float4*)(w + i + 4);
    s16x8 pk;
    pk[0]=(short)f2bf(a.x); pk[1]=(short)f2bf(a.y); pk[2]=(short)f2bf(a.z); pk[3]=(short)f2bf(a.w);
    pk[4]=(short)f2bf(b.x); pk[5]=(short)f2bf(b.y); pk[6]=(short)f2bf(b.z); pk[7]=(short)f2bf(b.w);
    *(s16x8*)(wb + i) = pk;
}

// ------------- kernel A: KV MFMA GEMM + exp + partial context ---------------
// grid 512 linear (XCD-swizzled), 256 thr. LDS: xtile 32768 + kv 18432 = 51200
__global__ __launch_bounds__(256,2)
void kvctx_kernel(const unsigned short* __restrict__ XT, const unsigned short* __restrict__ wb,
                  float* __restrict__ Cp, float* __restrict__ Zp)
{
    extern __shared__ char smraw[];
    unsigned short* xtile = (unsigned short*)smraw;            // [64][256]
    unsigned short* kv    = (unsigned short*)(smraw + 32768);  // [128][72]

    const int tid = threadIdx.x;
    const int w = tid >> 6, lane = tid & 63;
    const int l15 = lane & 15, q = lane >> 4;
    const int flat = blockIdx.x;
    const int qb  = flat & 63;     // b*4 + seg
    const int h   = flat >> 6;     // head
    const int b   = qb >> 2;
    const int seg = qb & 3;
    const int bh  = b*8 + h;

    // persistent W fragments: wave w owns KV rows w*32..w*32+31
    s16x8 aW[2][8];
    #pragma unroll
    for (int mf=0;mf<2;++mf){
        int rl = w*32 + mf*16 + l15;
        int grow = (rl < 64) ? (512 + h*64 + rl) : (1024 + h*64 + (rl-64));
        const unsigned short* wr = wb + (size_t)grow*256 + q*8;
        #pragma unroll
        for (int kc=0;kc<8;++kc)
            aW[mf][kc] = *(const s16x8*)(wr + kc*32);
    }

    f32x4 ctxacc[4];
    #pragma unroll
    for (int ef=0;ef<4;++ef) ctxacc[ef] = (f32x4){0.f,0.f,0.f,0.f};
    float zacc[8];
    #pragma unroll
    for (int i=0;i<8;++i) zacc[i]=0.f;

    const unsigned short* gsrc0 = XT + (size_t)b*XT_BSTRIDE + (size_t)(seg*1024)*256;

    {   // stage chunk 0
        const unsigned short* gs = gsrc0 + w*4096 + lane*8;
        #pragma unroll
        for (int j=0;j<8;++j)
            gload_lds16(gs + j*512, &xtile[w*4096 + j*512]);
    }
    __syncthreads();

    #pragma unroll 1
    for (int t=0;t<16;++t){
        // ---- KV GEMM (128 x 64 tile)
        f32x4 acc[2][4];
        #pragma unroll
        for (int mf=0;mf<2;++mf)
            #pragma unroll
            for (int nf=0;nf<4;++nf) acc[mf][nf]=(f32x4){0.f,0.f,0.f,0.f};
        #pragma unroll
        for (int kc=0;kc<8;++kc){
            s16x8 bf[4];
            #pragma unroll
            for (int nf=0;nf<4;++nf){
                int nl = nf*16 + l15;
                int blk = (kc*4 + q) ^ (nl & 7);
                bf[nf] = *(const s16x8*)&xtile[nl*256 + blk*8];
            }
            #pragma unroll
            for (int mf=0;mf<2;++mf)
                #pragma unroll
                for (int nf=0;nf<4;++nf)
                    acc[mf][nf] = MFMA(aW[mf][kc], bf[nf], acc[mf][nf]);
        }
        // ---- exp (K waves) + write KV tile to LDS [row][72]
        #pragma unroll
        for (int mf=0;mf<2;++mf){
            int row = w*32 + mf*16 + q*4;
            #pragma unroll
            for (int nf=0;nf<4;++nf){
                int col = nf*16 + l15;
                #pragma unroll
                for (int r=0;r<4;++r){
                    float v = acc[mf][nf][r];
                    if (w < 2){
                        v = __expf(v);
                        unsigned short bv = f2bf(v);
                        zacc[mf*4+r] += bf2f(bv);
                        kv[(row+r)*72 + col] = bv;
                    } else {
                        kv[(row+r)*72 + col] = f2bf(v);
                    }
                }
            }
        }
        __syncthreads();
        if (t < 15){   // prefetch next X tile, overlapped with ctx GEMM
            const unsigned short* gs = gsrc0 + (t+1)*16384 + w*4096 + lane*8;
            #pragma unroll
            for (int j=0;j<8;++j)
                gload_lds16(gs + j*512, &xtile[w*4096 + j*512]);
        }
        // ---- ctx GEMM: ctx[d,e] += expK[d,n] * V[e,n]
        #pragma unroll
        for (int kf=0;kf<2;++kf){
            s16x8 aC = *(const s16x8*)&kv[(w*16 + l15)*72 + kf*32 + q*8];
            #pragma unroll
            for (int ef=0;ef<4;++ef){
                s16x8 bC = *(const s16x8*)&kv[(64 + ef*16 + l15)*72 + kf*32 + q*8];
                ctxacc[ef] = MFMA(aC, bC, ctxacc[ef]);
            }
        }
        __syncthreads();
    }

    float* cpb = Cp + (size_t)(bh*4 + seg)*4096;
    #pragma unroll
    for (int ef=0;ef<4;++ef)
        #pragma unroll
        for (int r=0;r<4;++r){
            int d = w*16 + q*4 + r;
            cpb[d*64 + ef*16 + l15] = ctxacc[ef][r];
        }
    if (w < 2){
        #pragma unroll
        for (int i=0;i<8;++i){
            #pragma unroll
            for (int off=1; off<16; off<<=1)
                zacc[i] += __shfl_xor(zacc[i], off, 64);
        }
        if (l15 == 0){
            float* zpb = Zp + (size_t)(bh*4 + seg)*64;
            #pragma unroll
            for (int mf=0;mf<2;++mf)
                #pragma unroll
                for (int r=0;r<4;++r)
                    zpb[w*32 + mf*16 + q*4 + r] = zacc[mf*4+r];
        }
    }
}

// ------------- kernel B: reduce Cp/Zp + U = 0.125 * W_out ctx^T -------------
// grid (8 h, 16 b), 256 thr; LDS dyn 83456 B
__global__ __launch_bounds__(256)
void ctxu_kernel(const float* __restrict__ Cp, const float* __restrict__ Zp,
                 const float* __restrict__ wout, unsigned short* __restrict__ U)
{
    extern __shared__ char smraw[];
    float* wl = (float*)smraw;                  // [256][65]
    float* cl = (float*)(smraw + 66560);        // [64][65]
    float* zi = (float*)(smraw + 83200);        // [64]
    const int h = blockIdx.x, b = blockIdx.y, tid = threadIdx.x;
    const int bh = b*8 + h;
    {
        const float* wsrc = wout + (size_t)tid*512 + h*64;
        #pragma unroll
        for (int j=0;j<16;++j){
            float4 v = *(const float4*)(wsrc + j*4);
            wl[tid*65 + j*4+0]=v.x; wl[tid*65 + j*4+1]=v.y;
            wl[tid*65 + j*4+2]=v.z; wl[tid*65 + j*4+3]=v.w;
        }
    }
    if (tid < 64){
        float zs = 0.f;
        #pragma unroll
        for (int s=0;s<4;++s) zs += Zp[(bh*4+s)*64 + tid];
        zi[tid] = 1.f / (zs * 4096.f);
    }
    __syncthreads();
    {
        const int d = tid >> 2, e0 = (tid & 3) * 16;
        const float* cb = Cp + (size_t)(bh*4)*4096 + d*64 + e0;
        float v[16];
        #pragma unroll
        for (int j=0;j<16;++j) v[j]=0.f;
        #pragma unroll
        for (int s=0;s<4;++s){
            #pragma unroll
            for (int j4=0;j4<4;++j4){
                float4 t = *(const float4*)(cb + (size_t)s*4096 + j4*4);
                v[j4*4+0]+=t.x; v[j4*4+1]+=t.y; v[j4*4+2]+=t.z; v[j4*4+3]+=t.w;
            }
        }
        float zv = zi[d];
        #pragma unroll
        for (int j=0;j<16;++j) cl[d*65 + e0 + j] = v[j] * zv;
    }
    __syncthreads();
    const int d = tid & 63, og = tid >> 6;
    unsigned short* ub = U + (size_t)b*131072;
    #pragma unroll 1
    for (int k=0;k<64;++k){
        int o = og*64 + k;
        float s = 0.f;
        #pragma unroll
        for (int e=0;e<64;++e) s += wl[o*65+e]*cl[d*65+e];
        ub[(size_t)o*512 + h*64 + d] = f2bf(s * 0.125f);
    }
}

// ------------- kernel C: q MFMA -> softmax_d -> U MFMA -> bias -> LN --------
// grid (64 ntiles, 16 b), 256 thr. LDS dyn 70656 B
__global__ __launch_bounds__(256,2)
void qout_kernel(const unsigned short* __restrict__ XT, const unsigned short* __restrict__ wb,
                 const unsigned short* __restrict__ U, const float* __restrict__ bout,
                 const float* __restrict__ gg, float* __restrict__ out)
{
    extern __shared__ char smraw[];
    unsigned short* xtile = (unsigned short*)smraw;       // [64][256] (phase 1)
    unsigned short* qsm   = (unsigned short*)smraw;       // [64] rows, stride 520
    float* red = (float*)(smraw + 66560);                 // [256][2]
    float* bl  = (float*)(smraw + 68608);                 // [256]
    float* gl  = (float*)(smraw + 69632);                 // [256]

    const int tid = threadIdx.x;
    const int w = tid >> 6, lane = tid & 63, l15 = lane & 15, q = lane >> 4;
    const int b = blockIdx.y;
    const int n0 = blockIdx.x * 64;

    bl[tid] = bout[tid];
    gl[tid] = gg[tid];
    {
        const unsigned short* gs = XT + (size_t)b*XT_BSTRIDE + (size_t)n0*256 + w*4096 + lane*8;
        #pragma unroll
        for (int j=0;j<8;++j)
            gload_lds16(gs + j*512, &xtile[w*4096 + j*512]);
    }
    // pre-issue first q-weight fragments; latency hides under the barrier
    const unsigned short* wq = wb + (size_t)(w*128 + l15)*256 + q*8;
    s16x8 avA[8], avB[8];
    #pragma unroll
    for (int mf=0;mf<8;++mf) avA[mf] = *(const s16x8*)(wq + (size_t)mf*16*256);
    __syncthreads();

    // ---- q GEMM: wave w owns q rows w*128..+127, pipelined weight prefetch
    f32x4 acc[8][4];
    #pragma unroll
    for (int mf=0;mf<8;++mf)
        #pragma unroll
        for (int nf=0;nf<4;++nf) acc[mf][nf]=(f32x4){0.f,0.f,0.f,0.f};

    #pragma unroll 1
    for (int kc=0; kc<8; kc+=2){
        #pragma unroll
        for (int mf=0;mf<8;++mf) avB[mf] = *(const s16x8*)(wq + (size_t)mf*16*256 + (kc+1)*32);
        {
            s16x8 bf[4];
            #pragma unroll
            for (int nf=0;nf<4;++nf){
                int nl = nf*16 + l15;
                int blk = (kc*4 + q) ^ (nl & 7);
                bf[nf] = *(const s16x8*)&xtile[nl*256 + blk*8];
            }
            __builtin_amdgcn_s_setprio(1);
            #pragma unroll
            for (int mf=0;mf<8;++mf)
                #pragma unroll
                for (int nf=0;nf<4;++nf)
                    acc[mf][nf] = MFMA(avA[mf], bf[nf], acc[mf][nf]);
            __builtin_amdgcn_s_setprio(0);
        }
        if (kc+2 < 8){
            #pragma unroll
            for (int mf=0;mf<8;++mf) avA[mf] = *(const s16x8*)(wq + (size_t)mf*16*256 + (kc+2)*32);
        }
        {
            s16x8 bf[4];
            #pragma unroll
            for (int nf=0;nf<4;++nf){
                int nl = nf*16 + l15;
                int blk = ((kc+1)*4 + q) ^ (nl & 7);
                bf[nf] = *(const s16x8*)&xtile[nl*256 + blk*8];
            }
            __builtin_amdgcn_s_setprio(1);
            #pragma unroll
            for (int mf=0;mf<8;++mf)
                #pragma unroll
                for (int nf=0;nf<4;++nf)
                    acc[mf][nf] = MFMA(avB[mf], bf[nf], acc[mf][nf]);
            __builtin_amdgcn_s_setprio(0);
        }
    }

    // ---- softmax over d, per head per column (scale folded into U)
    #pragma unroll
    for (int hh=0;hh<2;++hh){
        #pragma unroll
        for (int nf=0;nf<4;++nf){
            float m = -1e30f;
            #pragma unroll
            for (int mf=0;mf<4;++mf)
                #pragma unroll
                for (int r=0;r<4;++r)
                    m = fmaxf(m, acc[hh*4+mf][nf][r]);
            m = fmaxf(m, __shfl_xor(m, 16, 64));
            m = fmaxf(m, __shfl_xor(m, 32, 64));
            float s = 0.f;
            #pragma unroll
            for (int mf=0;mf<4;++mf)
                #pragma unroll
                for (int r=0;r<4;++r){
                    float e = __expf(acc[hh*4+mf][nf][r] - m);
                    acc[hh*4+mf][nf][r] = e;
                    s += e;
                }
            s += __shfl_xor(s, 16, 64);
            s += __shfl_xor(s, 32, 64);
            float rs = 1.f / s;
            #pragma unroll
            for (int mf=0;mf<4;++mf)
                #pragma unroll
                for (int r=0;r<4;++r)
                    acc[hh*4+mf][nf][r] *= rs;
        }
    }
    __syncthreads();    // xtile reads done

    // ---- pack qsm via cvt_pk + ds_write_b64 (k = w*128+mf*16+q*4 .. +3)
    #pragma unroll
    for (int mf=0;mf<8;++mf){
        int dbase = w*128 + mf*16 + q*4;
        #pragma unroll
        for (int nf=0;nf<4;++nf){
            int n = nf*16 + l15;
            unsigned int lo = pack2bf(acc[mf][nf][0], acc[mf][nf][1]);
            unsigned int hi = pack2bf(acc[mf][nf][2], acc[mf][nf][3]);
            *(uint2*)&qsm[n*520 + dbase] = make_uint2(lo, hi);
        }
    }
    // pre-issue U fragments for kc=0,1; latency hides under pack+barrier
    const unsigned short* Ub = U + (size_t)b*131072 + (size_t)(w*64 + l15)*512 + q*8;
    s16x8 uvP[8];
    #pragma unroll
    for (int i=0;i<8;++i)
        uvP[i] = *(const s16x8*)(Ub + (size_t)(i&3)*16*512 + (i>>2)*32);
    __syncthreads();

    // ---- U GEMM: wave w owns out rows w*64..+63, fully unrolled K loop
    f32x4 yacc[4][4];
    #pragma unroll
    for (int mf=0;mf<4;++mf)
        #pragma unroll
        for (int nf=0;nf<4;++nf) yacc[mf][nf]=(f32x4){0.f,0.f,0.f,0.f};

    #pragma unroll
    for (int kc=0; kc<16; ++kc){
        s16x8 uv[4];
        #pragma unroll
        for (int mf=0;mf<4;++mf)
            uv[mf] = (kc < 2) ? uvP[(kc<<2)|mf]
                              : *(const s16x8*)(Ub + (size_t)mf*16*512 + kc*32);
        s16x8 bf[4];
        #pragma unroll
        for (int nf=0;nf<4;++nf){
            int n = nf*16 + l15;
            bf[nf] = *(const s16x8*)&qsm[n*520 + kc*32 + q*8];
        }
        __builtin_amdgcn_s_setprio(1);
        #pragma unroll
        for (int mf=0;mf<4;++mf)
            #pragma unroll
            for (int nf=0;nf<4;++nf)
                yacc[mf][nf] = MFMA(uv[mf], bf[nf], yacc[mf][nf]);
        __builtin_amdgcn_s_setprio(0);
    }

    // ---- bias
    #pragma unroll
    for (int mf=0;mf<4;++mf){
        int ob = w*64 + mf*16 + q*4;
        #pragma unroll
        for (int r=0;r<4;++r){
            float bo = bl[ob + r];
            #pragma unroll
            for (int nf=0;nf<4;++nf) yacc[mf][nf][r] += bo;
        }
    }
    // ---- LayerNorm over 256 channels
    float s1[4], s2[4];
    #pragma unroll
    for (int nf=0;nf<4;++nf){ s1[nf]=0.f; s2[nf]=0.f; }
    #pragma unroll
    for (int mf=0;mf<4;++mf)
        #pragma unroll
        for (int nf=0;nf<4;++nf)
            #pragma unroll
            for (int r=0;r<4;++r){
                float v = yacc[mf][nf][r];
                s1[nf] += v; s2[nf] += v*v;
            }
    #pragma unroll
    for (int nf=0;nf<4;++nf){
        s1[nf] += __shfl_xor(s1[nf], 16, 64);
        s1[nf] += __shfl_xor(s1[nf], 32, 64);
        s2[nf] += __shfl_xor(s2[nf], 16, 64);
        s2[nf] += __shfl_xor(s2[nf], 32, 64);
    }
    if (q == 0){
        #pragma unroll
        for (int nf=0;nf<4;++nf){
            int col = nf*16 + l15;
            red[(w*64 + col)*2 + 0] = s1[nf];
            red[(w*64 + col)*2 + 1] = s2[nf];
        }
    }
    __syncthreads();
    float mean_[4], inv_[4];
    #pragma unroll
    for (int nf=0;nf<4;++nf){
        int col = nf*16 + l15;
        float S1 = red[col*2] + red[(64+col)*2] + red[(128+col)*2] + red[(192+col)*2];
        float S2 = red[col*2+1] + red[(64+col)*2+1] + red[(128+col)*2+1] + red[(192+col)*2+1];
        float mn = S1 * (1.f/256.f);
        float vr = S2 * (1.f/256.f) - mn*mn;
        mean_[nf] = mn;
        inv_[nf] = rsqrtf(vr + 1e-5f);
    }
    float* ob = out + (size_t)b*1048576 + n0;
    #pragma unroll
    for (int mf=0;mf<4;++mf){
        #pragma unroll
        for (int r=0;r<4;++r){
            int o = w*64 + mf*16 + q*4 + r;
            float gv = gl[o];
            #pragma unroll
            for (int nf=0;nf<4;++nf){
                float val = (yacc[mf][nf][r] - mean_[nf]) * inv_[nf] * gv;
                ob[(size_t)o*4096 + nf*16 + l15] = val;
            }
        }
    }
}

// ----------------------------------------------------------------------------
extern "C" void kernel_launch(void* const* d_in, const int* in_sizes, int n_in,
                              void* d_out, int out_size, void* d_ws, size_t ws_size,
                              hipStream_t stream)
{
    const float* x    = (const float*)d_in[0];
    const float* wqkv = (const float*)d_in[1];
    const float* wout = (const float*)d_in[2];
    const float* bout = (const float*)d_in[3];
    const float* g    = (const float*)d_in[4];
    float* out = (float*)d_out;

    char* wsb = (char*)d_ws;
    unsigned short* XTs = (unsigned short*)wsb;
    unsigned short* wbf = (unsigned short*)(wsb + 33554432);
    unsigned short* Ubf = (unsigned short*)(wsb + 34340864);
    float* Cp  = (float*)(wsb + 38535168);
    float* Zp  = (float*)(wsb + 46923776);

    hipLaunchKernelGGL(xprep_kernel, dim3(64, 4, 16), dim3(256), 0,     stream, x, XTs);
    hipLaunchKernelGGL(wprep_kernel, dim3(192),       dim3(256), 0,     stream, wqkv, wbf);
    hipLaunchKernelGGL(kvctx_kernel, dim3(512),       dim3(256), 51200, stream, XTs, wbf, Cp, Zp);
    hipLaunchKernelGGL(ctxu_kernel,  dim3(8, 16),     dim3(256), 83456, stream, Cp, Zp, wout, Ubf);
    hipLaunchKernelGGL(qout_kernel,  dim3(64, 16),    dim3(256), 70656, stream, XTs, wbf, Ubf, bout, g, out);
}